// Round 6
// baseline (2260.226 us; speedup 1.0000x reference)
//
#include <hip/hip_runtime.h>
#include <hip/hip_fp16.h>
#include <math.h>

#define T_STEPS 8
#define F_IN    8
#define HID     32
#define KCH     5
#define PERIODS 8
#define NB      64     // nodes per step tile
#define WSLD    140
#define TSLD    68
#define MSCOPE  __HIP_MEMORY_SCOPE_AGENT

__device__ __forceinline__ float sigmoidf_(float x) { return 1.f / (1.f + __expf(-x)); }
__device__ __forceinline__ float tanhf_(float x) {
    float e = __expf(2.f * x);
    return 1.f - 2.f / (e + 1.f);
}

// ---- two-level grid barrier (16 sub-counters + main + generation) ----
// barcells: [0..511] sub counters (stride 32 ints), [512] main, [513] gen. Zeroed.
__device__ __forceinline__ void gbar_(int* bc, int target) {
    __syncthreads();
    if (threadIdx.x == 0) {
        __threadfence();
        int subsz = (int)(gridDim.x >> 4);
        int* sc = bc + (blockIdx.x & 15) * 32;
        int so = __hip_atomic_fetch_add(sc, 1, __ATOMIC_ACQ_REL, MSCOPE);
        if ((so % subsz) == subsz - 1) {
            int mo = __hip_atomic_fetch_add(bc + 512, 1, __ATOMIC_ACQ_REL, MSCOPE);
            if ((mo & 15) == 15)
                __hip_atomic_fetch_add(bc + 513, 1, __ATOMIC_RELEASE, MSCOPE);
        }
        while (__hip_atomic_load(bc + 513, __ATOMIC_RELAXED, MSCOPE) < target)
            __builtin_amdgcn_s_sleep(2);
        (void)__hip_atomic_load(bc + 513, __ATOMIC_ACQUIRE, MSCOPE);
    }
    __syncthreads();
}

// ---- block-0 exclusive scan (256 threads, 8 elems/thread/chunk); out[n]=total ----
__device__ void bscan_(const int* in, int* out, int n, int* lds) {
    int tid = threadIdx.x;
    int lane = tid & 63, wave = tid >> 6;
    int carry = 0;
    for (int base = 0; base < n; base += 2048) {
        int v[8];
        int s = 0;
        #pragma unroll
        for (int i = 0; i < 8; ++i) {
            int idx = base + tid * 8 + i;
            int t = (idx < n) ? in[idx] : 0;
            v[i] = t; s += t;
        }
        int incl = s;
        #pragma unroll
        for (int off = 1; off < 64; off <<= 1) {
            int t2 = __shfl_up(incl, off, 64);
            if (lane >= off) incl += t2;
        }
        if (lane == 63) lds[wave] = incl;
        __syncthreads();
        int wbase = 0;
        #pragma unroll
        for (int w = 0; w < 4; ++w) if (w < wave) wbase += lds[w];
        int tot = lds[0] + lds[1] + lds[2] + lds[3];
        int excl = carry + wbase + incl - s;
        #pragma unroll
        for (int i = 0; i < 8; ++i) {
            int idx = base + tid * 8 + i;
            if (idx < n) out[idx] = excl;
            excl += v[i];
        }
        carry += tot;
        __syncthreads();
    }
    if (tid == 0) out[n] = carry;
}

// ---- Laplacian phase: out[n][c] = alpha*sum_j val*x[col][c] + beta*xprev[n][c] ----
template <int C>
__device__ void lap_(__half* __restrict__ outp, const __half* __restrict__ xin,
                     const __half* __restrict__ xprev, float alpha, float beta,
                     const int* __restrict__ rowptr, const int2* __restrict__ cv, int N) {
    constexpr int Q = C / 8;
    int gsz = (int)(gridDim.x * 256);
    for (int i = blockIdx.x * 256 + threadIdx.x; i < N * Q; i += gsz) {
        int node = i / Q, q = i % Q;
        int beg = rowptr[node], end = rowptr[node + 1];
        float a0 = 0.f, a1 = 0.f, a2 = 0.f, a3 = 0.f, a4 = 0.f, a5 = 0.f, a6 = 0.f, a7 = 0.f;
        #pragma unroll 4
        for (int j = beg; j < end; ++j) {
            int2 p = cv[j];
            float nv = __int_as_float(p.y);
            float4 raw = *(const float4*)(xin + (size_t)p.x * C + q * 8);
            const __half2* h = (const __half2*)&raw;
            float2 f0 = __half22float2(h[0]);
            float2 f1 = __half22float2(h[1]);
            float2 f2 = __half22float2(h[2]);
            float2 f3 = __half22float2(h[3]);
            a0 += nv * f0.x; a1 += nv * f0.y; a2 += nv * f1.x; a3 += nv * f1.y;
            a4 += nv * f2.x; a5 += nv * f2.y; a6 += nv * f3.x; a7 += nv * f3.y;
        }
        size_t off = (size_t)node * C + q * 8;
        float r0 = alpha * a0, r1 = alpha * a1, r2 = alpha * a2, r3 = alpha * a3;
        float r4 = alpha * a4, r5 = alpha * a5, r6 = alpha * a6, r7 = alpha * a7;
        if (beta != 0.f) {
            float4 raw = *(const float4*)(xprev + off);
            const __half2* h = (const __half2*)&raw;
            float2 f0 = __half22float2(h[0]);
            float2 f1 = __half22float2(h[1]);
            float2 f2 = __half22float2(h[2]);
            float2 f3 = __half22float2(h[3]);
            r0 += beta * f0.x; r1 += beta * f0.y; r2 += beta * f1.x; r3 += beta * f1.y;
            r4 += beta * f2.x; r5 += beta * f2.y; r6 += beta * f3.x; r7 += beta * f3.y;
        }
        __half2 o[4];
        o[0] = __float22half2_rn(make_float2(r0, r1));
        o[1] = __float22half2_rn(make_float2(r2, r3));
        o[2] = __float22half2_rn(make_float2(r4, r5));
        o[3] = __float22half2_rn(make_float2(r6, r7));
        *(float4*)(outp + off) = *(float4*)o;
    }
}

// ================= mega kernel =================
__global__ void __launch_bounds__(256, 4) k_mega(
    const float* __restrict__ xall, const int* __restrict__ src, const int* __restrict__ dst,
    const float* __restrict__ Wx, const float* __restrict__ Wh,
    const float* __restrict__ w_c, const float* __restrict__ bg,
    const float* __restrict__ W_lin, const float* __restrict__ b_lin,
    float* __restrict__ out,
    int* degi, int* cnt, int* fill, int* hist, int* histbase,
    float* dis, int* perm, int* iperm, int* cntp, int* rowptr,
    int2* cv, __half* xb, __half* TXB, __half* THall, float* Cst,
    int* bar, int N, int E, int NT) {

    __shared__ float lds_f[8320];               // 33280 B; aliased per phase
    float* Ws = lds_f;                          // [40*140]
    float* Ts = lds_f + 5600;                   // [40*68]
    int* lds_i = (int*)lds_f;

    int tid = threadIdx.x;
    int gsz = (int)(gridDim.x * 256);
    int gtid = (int)(blockIdx.x * 256) + tid;
    int b = 0;

    // ---- P0: degree count ----
    for (int e = gtid; e < E; e += gsz) {
        int s = src[e], d = dst[e];
        if (s != d) {
            atomicAdd(&degi[s], 1);
            atomicAdd(&cnt[d], 1);
        }
    }
    gbar_(bar, ++b);

    // ---- P1: per-chunk degree histogram (bin-major layout) ----
    for (int c = blockIdx.x; c < NT; c += gridDim.x) {
        lds_i[tid] = 0;
        __syncthreads();
        int n = c * 256 + tid;
        if (n < N) atomicAdd(&lds_i[min(cnt[n], 255)], 1);
        __syncthreads();
        hist[tid * NT + c] = lds_i[tid];
        __syncthreads();
    }
    gbar_(bar, ++b);

    // ---- P2: scan histogram -> histbase ----
    if (blockIdx.x == 0) bscan_(hist, histbase, 256 * NT, lds_i);
    gbar_(bar, ++b);

    // ---- P3: counting-sort scatter (local ranks in LDS) + dis + cntp ----
    for (int c = blockIdx.x; c < NT; c += gridDim.x) {
        int n = c * 256 + tid;
        lds_i[tid] = (n < N) ? min(cnt[n], 255) : -1;
        __syncthreads();
        if (n < N) {
            int k = lds_i[tid], r = 0;
            for (int j = 0; j < tid; ++j) r += (lds_i[j] == k);
            int pos = histbase[k * NT + c] + r;
            perm[pos] = n;
            iperm[n] = pos;
            cntp[pos] = cnt[n];
            int dg = degi[n];
            dis[n] = (dg > 0) ? rsqrtf((float)dg) : 0.f;
        }
        __syncthreads();
    }
    gbar_(bar, ++b);

    // ---- P4: scan cntp -> rowptr ----
    if (blockIdx.x == 0) bscan_(cntp, rowptr, N, lds_i);
    gbar_(bar, ++b);

    // ---- P5: edge scatter into permuted CSR + x transpose/permute/fp16 ----
    for (int e = gtid; e < E; e += gsz) {
        int s = src[e], d = dst[e];
        if (s != d) {
            float nv = -dis[s] * dis[d];
            int dp = iperm[d];
            int p = atomicAdd(&fill[dp], 1);
            cv[rowptr[dp] + p] = make_int2(iperm[s], __float_as_int(nv));
        }
    }
    for (int i = gtid; i < N * T_STEPS; i += gsz) {
        int n = i >> 3, t = i & 7;
        float4 a = *(const float4*)(xall + ((size_t)t * N + n) * 8);
        float4 bb = *(const float4*)(xall + ((size_t)t * N + n) * 8 + 4);
        __half2 h[4];
        h[0] = __float22half2_rn(make_float2(a.x, a.y));
        h[1] = __float22half2_rn(make_float2(a.z, a.w));
        h[2] = __float22half2_rn(make_float2(bb.x, bb.y));
        h[3] = __float22half2_rn(make_float2(bb.z, bb.w));
        *(float4*)(xb + (size_t)iperm[n] * 64 + t * 8) = *(float4*)h;
    }
    gbar_(bar, ++b);

    // ---- P6: batched x-phase Chebyshev (C=64, all 8 timesteps at once) ----
    __half* TXB0 = TXB;
    __half* TXB1 = TXB + (size_t)N * 64;
    __half* TXB2 = TXB + (size_t)2 * N * 64;
    __half* TXB3 = TXB + (size_t)3 * N * 64;
    lap_<64>(TXB0, xb,   nullptr, 1.f,  0.f, rowptr, cv, N); gbar_(bar, ++b);
    lap_<64>(TXB1, TXB0, xb,      2.f, -1.f, rowptr, cv, N); gbar_(bar, ++b);
    lap_<64>(TXB2, TXB1, TXB0,    2.f, -1.f, rowptr, cv, N); gbar_(bar, ++b);
    lap_<64>(TXB3, TXB2, TXB1,    2.f, -1.f, rowptr, cv, N); gbar_(bar, ++b);

    // ---- P7: time loop ----
    __half* TH0 = THall;
    __half* TH1 = THall + (size_t)N * HID;
    __half* TH2 = THall + (size_t)2 * N * HID;
    __half* TH3 = THall + (size_t)3 * N * HID;
    __half* TH4 = THall + (size_t)4 * N * HID;
    int ntiles = (N + NB - 1) / NB;
    int og = tid & 15;
    int o0 = og * 8;
    int h0 = og * 2;
    int n0 = (tid >> 4) * 4;
    int wp0 = o0 + 4 * (o0 >> 5);

    for (int t = 0; t < T_STEPS; ++t) {
        if (t > 0) {
            lap_<HID>(TH1, TH0, nullptr, 1.f,  0.f, rowptr, cv, N); gbar_(bar, ++b);
            lap_<HID>(TH2, TH1, TH0,     2.f, -1.f, rowptr, cv, N); gbar_(bar, ++b);
            lap_<HID>(TH3, TH2, TH1,     2.f, -1.f, rowptr, cv, N); gbar_(bar, ++b);
            lap_<HID>(TH4, TH3, TH2,     2.f, -1.f, rowptr, cv, N); gbar_(bar, ++b);
        } else {
            gbar_(bar, ++b); gbar_(bar, ++b); gbar_(bar, ++b); gbar_(bar, ++b);
        }

        // ---- step: fused gate GEMM + LSTM pointwise ----
        for (int tile = blockIdx.x; tile < ntiles; tile += gridDim.x) {
            __syncthreads();                     // protect LDS reuse across tiles
            int base = tile * NB;
            float acc[4][8];
            #pragma unroll
            for (int oj = 0; oj < 8; ++oj) {
                float bb = bg[(oj & 3) * 32 + h0 + (oj >> 2)];
                #pragma unroll
                for (int nj = 0; nj < 4; ++nj) acc[nj][oj] = bb;
            }

            // chunk 0: x-terms (40 rows = 5 k x 8 ch)
            for (int i = tid; i < 40 * 128; i += 256) {
                int ci = i >> 7, o = i & 127;
                int k = ci >> 3, c = ci & 7, h = o >> 2, g = o & 3;
                Ws[ci * WSLD + o + 4 * (o >> 5)] = Wx[(((g * KCH + k) * 8) + c) * 32 + h];
            }
            for (int i = tid; i < NB * 5; i += 256) {
                int nl = i / 5, k = i % 5;
                int node = base + nl; if (node >= N) node = N - 1;
                const __half* sp = (k == 0) ? (xb + (size_t)node * 64 + t * 8)
                                            : (TXB + ((size_t)(k - 1) * N + node) * 64 + t * 8);
                float4 raw = *(const float4*)sp;
                const __half2* h = (const __half2*)&raw;
                float2 f0 = __half22float2(h[0]);
                float2 f1 = __half22float2(h[1]);
                float2 f2 = __half22float2(h[2]);
                float2 f3 = __half22float2(h[3]);
                int row = k * 8;
                Ts[(row + 0) * TSLD + nl] = f0.x; Ts[(row + 1) * TSLD + nl] = f0.y;
                Ts[(row + 2) * TSLD + nl] = f1.x; Ts[(row + 3) * TSLD + nl] = f1.y;
                Ts[(row + 4) * TSLD + nl] = f2.x; Ts[(row + 5) * TSLD + nl] = f2.y;
                Ts[(row + 6) * TSLD + nl] = f3.x; Ts[(row + 7) * TSLD + nl] = f3.y;
            }
            __syncthreads();
            #pragma unroll 4
            for (int c = 0; c < 40; ++c) {
                float4 wA = *(const float4*)(Ws + c * WSLD + wp0);
                float4 wB = *(const float4*)(Ws + c * WSLD + wp0 + 4);
                float4 tA = *(const float4*)(Ts + c * TSLD + n0);
                float wv[8] = {wA.x, wA.y, wA.z, wA.w, wB.x, wB.y, wB.z, wB.w};
                float tv[4] = {tA.x, tA.y, tA.z, tA.w};
                #pragma unroll
                for (int nj = 0; nj < 4; ++nj)
                    #pragma unroll
                    for (int oj = 0; oj < 8; ++oj)
                        acc[nj][oj] += tv[nj] * wv[oj];
            }

            if (t > 0) {   // H-terms are all zero at t=0 (H0 = 0)
                for (int k = 0; k < KCH; ++k) {
                    __syncthreads();
                    for (int i = tid; i < 32 * 128; i += 256) {
                        int ci = i >> 7, o = i & 127;
                        int h = o >> 2, g = o & 3;
                        Ws[ci * WSLD + o + 4 * (o >> 5)] = Wh[(((g * KCH + k) * 32) + ci) * 32 + h];
                    }
                    for (int i = tid; i < NB * 4; i += 256) {
                        int nl = i >> 2, qq = i & 3;
                        int node = base + nl; if (node >= N) node = N - 1;
                        float4 raw = *(const float4*)(THall + ((size_t)k * N + node) * 32 + qq * 8);
                        const __half2* h = (const __half2*)&raw;
                        float2 f0 = __half22float2(h[0]);
                        float2 f1 = __half22float2(h[1]);
                        float2 f2 = __half22float2(h[2]);
                        float2 f3 = __half22float2(h[3]);
                        int row = qq * 8;
                        Ts[(row + 0) * TSLD + nl] = f0.x; Ts[(row + 1) * TSLD + nl] = f0.y;
                        Ts[(row + 2) * TSLD + nl] = f1.x; Ts[(row + 3) * TSLD + nl] = f1.y;
                        Ts[(row + 4) * TSLD + nl] = f2.x; Ts[(row + 5) * TSLD + nl] = f2.y;
                        Ts[(row + 6) * TSLD + nl] = f3.x; Ts[(row + 7) * TSLD + nl] = f3.y;
                    }
                    __syncthreads();
                    #pragma unroll 4
                    for (int c = 0; c < 32; ++c) {
                        float4 wA = *(const float4*)(Ws + c * WSLD + wp0);
                        float4 wB = *(const float4*)(Ws + c * WSLD + wp0 + 4);
                        float4 tA = *(const float4*)(Ts + c * TSLD + n0);
                        float wv[8] = {wA.x, wA.y, wA.z, wA.w, wB.x, wB.y, wB.z, wB.w};
                        float tv[4] = {tA.x, tA.y, tA.z, tA.w};
                        #pragma unroll
                        for (int nj = 0; nj < 4; ++nj)
                            #pragma unroll
                            for (int oj = 0; oj < 8; ++oj)
                                acc[nj][oj] += tv[nj] * wv[oj];
                    }
                }
            }

            // LSTM pointwise, register-local
            float wci0 = w_c[h0],      wci1 = w_c[h0 + 1];
            float wcf0 = w_c[32 + h0], wcf1 = w_c[32 + h0 + 1];
            float wco0 = w_c[64 + h0], wco1 = w_c[64 + h0 + 1];
            #pragma unroll
            for (int nj = 0; nj < 4; ++nj) {
                int node = base + n0 + nj;
                if (node < N) {
                    size_t idx = (size_t)node * 32 + h0;
                    float2 Co = *(const float2*)(Cst + idx);
                    float2 Cn2, Hn;
                    {
                        float I  = sigmoidf_(acc[nj][0] + wci0 * Co.x);
                        float F  = sigmoidf_(acc[nj][1] + wcf0 * Co.x);
                        float Tg = tanhf_(acc[nj][2]);
                        float Cn = F * Co.x + I * Tg;
                        float O  = sigmoidf_(acc[nj][3] + wco0 * Cn);
                        Cn2.x = Cn; Hn.x = O * tanhf_(Cn);
                    }
                    {
                        float I  = sigmoidf_(acc[nj][4] + wci1 * Co.y);
                        float F  = sigmoidf_(acc[nj][5] + wcf1 * Co.y);
                        float Tg = tanhf_(acc[nj][6]);
                        float Cn = F * Co.y + I * Tg;
                        float O  = sigmoidf_(acc[nj][7] + wco1 * Cn);
                        Cn2.y = Cn; Hn.y = O * tanhf_(Cn);
                    }
                    *(float2*)(Cst + idx) = Cn2;
                    *(__half2*)(THall + idx) = __float22half2_rn(make_float2(Hn.x, Hn.y));
                }
            }
        }
        gbar_(bar, ++b);
    }

    // ---- P8: output head (one node per thread) ----
    for (int i = gtid; i < N; i += gsz) {
        float hrow[HID];
        const __half* Hp = TH0 + (size_t)i * HID;
        #pragma unroll
        for (int h = 0; h < HID; h += 8) {
            float4 raw = *(const float4*)(Hp + h);
            const __half2* hh = (const __half2*)&raw;
            float2 f0 = __half22float2(hh[0]);
            float2 f1 = __half22float2(hh[1]);
            float2 f2 = __half22float2(hh[2]);
            float2 f3 = __half22float2(hh[3]);
            hrow[h + 0] = fmaxf(f0.x, 0.f); hrow[h + 1] = fmaxf(f0.y, 0.f);
            hrow[h + 2] = fmaxf(f1.x, 0.f); hrow[h + 3] = fmaxf(f1.y, 0.f);
            hrow[h + 4] = fmaxf(f2.x, 0.f); hrow[h + 5] = fmaxf(f2.y, 0.f);
            hrow[h + 6] = fmaxf(f3.x, 0.f); hrow[h + 7] = fmaxf(f3.y, 0.f);
        }
        float o[PERIODS];
        #pragma unroll
        for (int p = 0; p < PERIODS; ++p) {
            float acc = b_lin[p];
            #pragma unroll
            for (int h = 0; h < HID; ++h) acc += hrow[h] * W_lin[p * HID + h];
            o[p] = acc;
        }
        float* op = out + (size_t)perm[i] * PERIODS;
        *(float4*)op = make_float4(o[0], o[1], o[2], o[3]);
        *(float4*)(op + 4) = make_float4(o[4], o[5], o[6], o[7]);
    }
}

// ---------------- launch ----------------

extern "C" void kernel_launch(void* const* d_in, const int* in_sizes, int n_in,
                              void* d_out, int out_size, void* d_ws, size_t ws_size,
                              hipStream_t stream) {
    const float* xall  = (const float*)d_in[0];
    const int*   ei    = (const int*)d_in[1];
    const float* Wx    = (const float*)d_in[2];
    const float* Wh    = (const float*)d_in[3];
    const float* w_c   = (const float*)d_in[4];
    const float* bg    = (const float*)d_in[5];
    const float* W_lin = (const float*)d_in[6];
    const float* b_lin = (const float*)d_in[7];
    float* out = (float*)d_out;

    const int E = in_sizes[1] / 2;
    const int N = in_sizes[0] / (T_STEPS * F_IN);
    const int NT = (N + 255) / 256;
    const int* src = ei;
    const int* dst = ei + E;

    char* p = (char*)d_ws;
    auto carve = [&](size_t bytes) -> void* {
        void* r = (void*)p;
        p += (bytes + 255) & ~(size_t)255;
        return r;
    };
    // zero block: degi, cnt, fill, barrier cells, Cst, THall slice 0 (= H0)
    char* zero_begin = p;
    int*    degi  = (int*)   carve((size_t)N * 4);
    int*    cnt   = (int*)   carve((size_t)N * 4);
    int*    fill  = (int*)   carve((size_t)N * 4);
    int*    bar   = (int*)   carve(514 * 4);
    float*  Cst   = (float*) carve((size_t)N * HID * 4);
    __half* THall = (__half*)carve((size_t)KCH * N * HID * 2);
    size_t zero_bytes = (size_t)((char*)THall - zero_begin) + (size_t)N * HID * 2;
    int*    hist     = (int*)   carve((size_t)256 * NT * 4);
    int*    histbase = (int*)   carve(((size_t)256 * NT + 1) * 4);
    float*  dis      = (float*) carve((size_t)N * 4);
    int*    perm     = (int*)   carve((size_t)N * 4);
    int*    iperm    = (int*)   carve((size_t)N * 4);
    int*    cntp     = (int*)   carve((size_t)N * 4);
    int*    rowptr   = (int*)   carve((size_t)(N + 1) * 4);
    int2*   cv       = (int2*)  carve((size_t)E * 8);
    __half* xb       = (__half*)carve((size_t)N * 64 * 2);
    __half* TXB      = (__half*)carve((size_t)4 * N * 64 * 2);

    hipMemsetAsync(zero_begin, 0, zero_bytes, stream);

    int dev = 0;
    hipGetDevice(&dev);
    hipDeviceProp_t prop;
    hipGetDeviceProperties(&prop, dev);
    int occ = 0;
    hipOccupancyMaxActiveBlocksPerMultiprocessor(&occ, k_mega, 256, 0);
    if (occ < 1) occ = 1;
    long grid_l = (long)occ * prop.multiProcessorCount;
    int grid = (grid_l > 1024) ? 1024 : (int)grid_l;
    grid &= ~15;
    if (grid < 16) grid = 16;

    void* args[] = {
        (void*)&xall, (void*)&src, (void*)&dst, (void*)&Wx, (void*)&Wh,
        (void*)&w_c, (void*)&bg, (void*)&W_lin, (void*)&b_lin, (void*)&out,
        (void*)&degi, (void*)&cnt, (void*)&fill, (void*)&hist, (void*)&histbase,
        (void*)&dis, (void*)&perm, (void*)&iperm, (void*)&cntp, (void*)&rowptr,
        (void*)&cv, (void*)&xb, (void*)&TXB, (void*)&THall, (void*)&Cst,
        (void*)&bar, (void*)&N, (void*)&E, (void*)&NT
    };
    hipLaunchCooperativeKernel(k_mega, dim3(grid), dim3(256), args, 0, stream);
}

// Round 7
// 724.955 us; speedup vs baseline: 3.1177x; 3.1177x over previous
//
#include <hip/hip_runtime.h>
#include <hip/hip_fp16.h>
#include <math.h>

#define T_STEPS 8
#define F_IN    8
#define HID     32
#define KCH     5
#define PERIODS 8
#define NB      64
#define WSLD    140
#define TSLD    68

__device__ __forceinline__ float sigmoidf_(float x) { return 1.f / (1.f + __expf(-x)); }
__device__ __forceinline__ float tanhf_(float x) {
    float e = __expf(2.f * x);
    return 1.f - 2.f / (e + 1.f);
}

// ---------------- graph setup ----------------

__global__ void k_count(const int* __restrict__ src, const int* __restrict__ dst,
                        int* __restrict__ degi, int* __restrict__ cnt, int E) {
    int e = blockIdx.x * blockDim.x + threadIdx.x;
    if (e >= E) return;
    int s = src[e], d = dst[e];
    if (s != d) {
        atomicAdd(&degi[s], 1);
        atomicAdd(&cnt[d], 1);
    }
}

// block-local degree histogram, bin-major output: hist[bin*NT + blk]
__global__ void k_hist2(const int* __restrict__ cnt, int* __restrict__ hist,
                        int N, int NT) {
    __shared__ int h[256];
    int tid = threadIdx.x, blk = blockIdx.x;
    h[tid] = 0;
    __syncthreads();
    int n = blk * 256 + tid;
    if (n < N) atomicAdd(&h[min(cnt[n], 255)], 1);
    __syncthreads();
    hist[tid * NT + blk] = h[tid];
}

// exclusive scan, single block 1024 threads, 32 elems/thread; valid n <= 32768
__global__ void __launch_bounds__(1024) k_scan(const int* __restrict__ in,
                                               int* __restrict__ outp, int n) {
    __shared__ int wsum[16];
    int tid = threadIdx.x;
    int base = tid * 32;
    int v[32];
    int s = 0;
    #pragma unroll
    for (int i = 0; i < 32; ++i) {
        int idx = base + i;
        int t = (idx < n) ? in[idx] : 0;
        v[i] = t; s += t;
    }
    int lane = tid & 63, wave = tid >> 6;
    int incl = s;
    #pragma unroll
    for (int off = 1; off < 64; off <<= 1) {
        int t = __shfl_up(incl, off, 64);
        if (lane >= off) incl += t;
    }
    if (lane == 63) wsum[wave] = incl;
    __syncthreads();
    if (tid < 64) {
        int w = (tid < 16) ? wsum[tid] : 0;
        int iw = w;
        #pragma unroll
        for (int off = 1; off < 16; off <<= 1) {
            int t = __shfl_up(iw, off, 64);
            if (tid >= off) iw += t;
        }
        if (tid < 16) wsum[tid] = iw - w;
    }
    __syncthreads();
    int excl = wsum[wave] + (incl - s);
    #pragma unroll
    for (int i = 0; i < 32; ++i) {
        int idx = base + i;
        if (idx < n) outp[idx] = excl;
        excl += v[i];
    }
    if (tid == 1023) outp[n] = wsum[15] + incl;
}

// counting-sort scatter with block-local ranks (no global atomics) + dis + cntp
__global__ void k_permscat2(const int* __restrict__ cnt, const int* __restrict__ degi,
                            const int* __restrict__ histbase,
                            int* __restrict__ perm, int* __restrict__ iperm,
                            int* __restrict__ cntp, float* __restrict__ dis,
                            int N, int NT) {
    __shared__ int key[256];
    int tid = threadIdx.x, blk = blockIdx.x;
    int n = blk * 256 + tid;
    int k = (n < N) ? min(cnt[n], 255) : -1;
    key[tid] = k;
    __syncthreads();
    if (n < N) {
        int r = 0;
        for (int j = 0; j < tid; ++j) r += (key[j] == k);   // LDS broadcast loop
        int pos = histbase[k * NT + blk] + r;
        perm[pos] = n;
        iperm[n] = pos;
        cntp[pos] = cnt[n];
        int dg = degi[n];
        dis[n] = (dg > 0) ? rsqrtf((float)dg) : 0.f;
    }
}

// edge scatter into permuted CSR; packs (permuted col, -norm)
__global__ void k_scatter(const int* __restrict__ src, const int* __restrict__ dst,
                          const float* __restrict__ dis, const int* __restrict__ rowptr,
                          const int* __restrict__ iperm, int* __restrict__ fill,
                          int2* __restrict__ cv, int E) {
    int e = blockIdx.x * blockDim.x + threadIdx.x;
    if (e >= E) return;
    int s = src[e], d = dst[e];
    if (s == d) return;
    float nv = -dis[s] * dis[d];
    int dp = iperm[d];
    int p = atomicAdd(&fill[dp], 1);
    cv[rowptr[dp] + p] = make_int2(iperm[s], __float_as_int(nv));
}

// transpose + permute + fp16-pack x: [T][N][8] f32 -> xb [Np][64] half
__global__ void k_xt(const float* __restrict__ xall, const int* __restrict__ iperm,
                     __half* __restrict__ xb, int N) {
    int i = blockIdx.x * blockDim.x + threadIdx.x;
    if (i >= N * T_STEPS) return;
    int n = i >> 3, t = i & 7;
    float4 a = *(const float4*)(xall + ((size_t)t * N + n) * 8);
    float4 b = *(const float4*)(xall + ((size_t)t * N + n) * 8 + 4);
    __half2 h[4];
    h[0] = __float22half2_rn(make_float2(a.x, a.y));
    h[1] = __float22half2_rn(make_float2(a.z, a.w));
    h[2] = __float22half2_rn(make_float2(b.x, b.y));
    h[3] = __float22half2_rn(make_float2(b.z, b.w));
    *(float4*)(xb + (size_t)iperm[n] * 64 + t * 8) = *(float4*)h;
}

// ---------------- Laplacian: pull CSR, fp16 features, 2-way edge split ------
// out[n][c] = alpha * sum_j val[j]*x[col[j]][c] + beta * xprev[n][c]
// Node group = Q*2 lanes: q = channel slice (8 halves), s = edge parity.
template <int C>
__global__ void __launch_bounds__(256) k_lap_h(__half* __restrict__ outp,
                                               const __half* __restrict__ xin,
                                               const __half* __restrict__ xprev,
                                               float alpha, float beta,
                                               const int* __restrict__ rowptr,
                                               const int2* __restrict__ cv, int N) {
    constexpr int Q = C / 8;
    constexpr int W = Q * 2;
    int idx = blockIdx.x * 256 + threadIdx.x;
    int node = idx / W;
    int r = idx % W;
    int q = r % Q, s = r / Q;
    if (node >= N) return;
    int beg = rowptr[node], end = rowptr[node + 1];
    float a0 = 0.f, a1 = 0.f, a2 = 0.f, a3 = 0.f, a4 = 0.f, a5 = 0.f, a6 = 0.f, a7 = 0.f;
    #pragma unroll 4
    for (int j = beg + s; j < end; j += 2) {
        int2 p = cv[j];
        float nv = __int_as_float(p.y);
        float4 raw = *(const float4*)(xin + (size_t)p.x * C + q * 8);
        const __half2* h = (const __half2*)&raw;
        float2 f0 = __half22float2(h[0]);
        float2 f1 = __half22float2(h[1]);
        float2 f2 = __half22float2(h[2]);
        float2 f3 = __half22float2(h[3]);
        a0 += nv * f0.x; a1 += nv * f0.y; a2 += nv * f1.x; a3 += nv * f1.y;
        a4 += nv * f2.x; a5 += nv * f2.y; a6 += nv * f3.x; a7 += nv * f3.y;
    }
    // combine edge-parity partner (xor mask Q stays inside the node group)
    a0 += __shfl_xor(a0, Q, 64); a1 += __shfl_xor(a1, Q, 64);
    a2 += __shfl_xor(a2, Q, 64); a3 += __shfl_xor(a3, Q, 64);
    a4 += __shfl_xor(a4, Q, 64); a5 += __shfl_xor(a5, Q, 64);
    a6 += __shfl_xor(a6, Q, 64); a7 += __shfl_xor(a7, Q, 64);
    if (s != 0) return;
    size_t off = (size_t)node * C + q * 8;
    float r0 = alpha * a0, r1 = alpha * a1, r2 = alpha * a2, r3 = alpha * a3;
    float r4 = alpha * a4, r5 = alpha * a5, r6 = alpha * a6, r7 = alpha * a7;
    if (beta != 0.f) {
        float4 raw = *(const float4*)(xprev + off);
        const __half2* h = (const __half2*)&raw;
        float2 f0 = __half22float2(h[0]);
        float2 f1 = __half22float2(h[1]);
        float2 f2 = __half22float2(h[2]);
        float2 f3 = __half22float2(h[3]);
        r0 += beta * f0.x; r1 += beta * f0.y; r2 += beta * f1.x; r3 += beta * f1.y;
        r4 += beta * f2.x; r5 += beta * f2.y; r6 += beta * f3.x; r7 += beta * f3.y;
    }
    __half2 o[4];
    o[0] = __float22half2_rn(make_float2(r0, r1));
    o[1] = __float22half2_rn(make_float2(r2, r3));
    o[2] = __float22half2_rn(make_float2(r4, r5));
    o[3] = __float22half2_rn(make_float2(r6, r7));
    *(float4*)(outp + off) = *(float4*)o;
}

// ---------------- fused gate GEMM + LSTM pointwise (register-blocked) --------
__global__ void __launch_bounds__(256) k_step(
    const __half* __restrict__ xb, const __half* __restrict__ TXB,
    __half* __restrict__ THall, float* __restrict__ Cst,
    const float* __restrict__ Wx, const float* __restrict__ Wh,
    const float* __restrict__ w_c, const float* __restrict__ bg,
    int t, int withH, int N) {
    __shared__ float Ws[40 * WSLD];
    __shared__ float Ts[40 * TSLD];
    int tid = threadIdx.x;
    int base = blockIdx.x * NB;
    int og = tid & 15;
    int o0 = og * 8;
    int h0 = og * 2;
    int n0 = (tid >> 4) * 4;
    int wp0 = o0 + 4 * (o0 >> 5);

    float acc[4][8];
    #pragma unroll
    for (int oj = 0; oj < 8; ++oj) {
        float b = bg[(oj & 3) * 32 + h0 + (oj >> 2)];
        #pragma unroll
        for (int nj = 0; nj < 4; ++nj) acc[nj][oj] = b;
    }

    // ---- chunk 0: x-terms (40 rows = 5 k x 8 ch) ----
    for (int i = tid; i < 40 * 128; i += 256) {
        int ci = i >> 7, o = i & 127;
        int k = ci >> 3, c = ci & 7, h = o >> 2, g = o & 3;
        Ws[ci * WSLD + o + 4 * (o >> 5)] = Wx[(((g * KCH + k) * 8) + c) * 32 + h];
    }
    for (int i = tid; i < NB * 5; i += 256) {
        int nl = i / 5, k = i % 5;
        int node = base + nl; if (node >= N) node = N - 1;
        const __half* sp = (k == 0) ? (xb + (size_t)node * 64 + t * 8)
                                    : (TXB + ((size_t)(k - 1) * N + node) * 64 + t * 8);
        float4 raw = *(const float4*)sp;
        const __half2* h = (const __half2*)&raw;
        float2 f0 = __half22float2(h[0]);
        float2 f1 = __half22float2(h[1]);
        float2 f2 = __half22float2(h[2]);
        float2 f3 = __half22float2(h[3]);
        int row = k * 8;
        Ts[(row + 0) * TSLD + nl] = f0.x; Ts[(row + 1) * TSLD + nl] = f0.y;
        Ts[(row + 2) * TSLD + nl] = f1.x; Ts[(row + 3) * TSLD + nl] = f1.y;
        Ts[(row + 4) * TSLD + nl] = f2.x; Ts[(row + 5) * TSLD + nl] = f2.y;
        Ts[(row + 6) * TSLD + nl] = f3.x; Ts[(row + 7) * TSLD + nl] = f3.y;
    }
    __syncthreads();
    #pragma unroll 4
    for (int c = 0; c < 40; ++c) {
        float4 wA = *(const float4*)(Ws + c * WSLD + wp0);
        float4 wB = *(const float4*)(Ws + c * WSLD + wp0 + 4);
        float4 tA = *(const float4*)(Ts + c * TSLD + n0);
        float wv[8] = {wA.x, wA.y, wA.z, wA.w, wB.x, wB.y, wB.z, wB.w};
        float tv[4] = {tA.x, tA.y, tA.z, tA.w};
        #pragma unroll
        for (int nj = 0; nj < 4; ++nj)
            #pragma unroll
            for (int oj = 0; oj < 8; ++oj)
                acc[nj][oj] += tv[nj] * wv[oj];
    }

    // ---- chunks 1..5: H-terms (skipped when t==0, H0 = 0) ----
    if (withH) {
        for (int k = 0; k < KCH; ++k) {
            __syncthreads();
            for (int i = tid; i < 32 * 128; i += 256) {
                int ci = i >> 7, o = i & 127;
                int h = o >> 2, g = o & 3;
                Ws[ci * WSLD + o + 4 * (o >> 5)] = Wh[(((g * KCH + k) * 32) + ci) * 32 + h];
            }
            for (int i = tid; i < NB * 4; i += 256) {
                int nl = i >> 2, qq = i & 3;
                int node = base + nl; if (node >= N) node = N - 1;
                float4 raw = *(const float4*)(THall + ((size_t)k * N + node) * 32 + qq * 8);
                const __half2* h = (const __half2*)&raw;
                float2 f0 = __half22float2(h[0]);
                float2 f1 = __half22float2(h[1]);
                float2 f2 = __half22float2(h[2]);
                float2 f3 = __half22float2(h[3]);
                int row = qq * 8;
                Ts[(row + 0) * TSLD + nl] = f0.x; Ts[(row + 1) * TSLD + nl] = f0.y;
                Ts[(row + 2) * TSLD + nl] = f1.x; Ts[(row + 3) * TSLD + nl] = f1.y;
                Ts[(row + 4) * TSLD + nl] = f2.x; Ts[(row + 5) * TSLD + nl] = f2.y;
                Ts[(row + 6) * TSLD + nl] = f3.x; Ts[(row + 7) * TSLD + nl] = f3.y;
            }
            __syncthreads();
            #pragma unroll 4
            for (int c = 0; c < 32; ++c) {
                float4 wA = *(const float4*)(Ws + c * WSLD + wp0);
                float4 wB = *(const float4*)(Ws + c * WSLD + wp0 + 4);
                float4 tA = *(const float4*)(Ts + c * TSLD + n0);
                float wv[8] = {wA.x, wA.y, wA.z, wA.w, wB.x, wB.y, wB.z, wB.w};
                float tv[4] = {tA.x, tA.y, tA.z, tA.w};
                #pragma unroll
                for (int nj = 0; nj < 4; ++nj)
                    #pragma unroll
                    for (int oj = 0; oj < 8; ++oj)
                        acc[nj][oj] += tv[nj] * wv[oj];
            }
        }
    }

    // ---- LSTM pointwise, register-local ----
    float wci0 = w_c[h0],      wci1 = w_c[h0 + 1];
    float wcf0 = w_c[32 + h0], wcf1 = w_c[32 + h0 + 1];
    float wco0 = w_c[64 + h0], wco1 = w_c[64 + h0 + 1];
    #pragma unroll
    for (int nj = 0; nj < 4; ++nj) {
        int node = base + n0 + nj;
        if (node < N) {
            size_t idx = (size_t)node * 32 + h0;
            float2 Co = *(const float2*)(Cst + idx);
            float2 Cn2, Hn;
            {
                float I  = sigmoidf_(acc[nj][0] + wci0 * Co.x);
                float F  = sigmoidf_(acc[nj][1] + wcf0 * Co.x);
                float Tg = tanhf_(acc[nj][2]);
                float Cn = F * Co.x + I * Tg;
                float O  = sigmoidf_(acc[nj][3] + wco0 * Cn);
                Cn2.x = Cn; Hn.x = O * tanhf_(Cn);
            }
            {
                float I  = sigmoidf_(acc[nj][4] + wci1 * Co.y);
                float F  = sigmoidf_(acc[nj][5] + wcf1 * Co.y);
                float Tg = tanhf_(acc[nj][6]);
                float Cn = F * Co.y + I * Tg;
                float O  = sigmoidf_(acc[nj][7] + wco1 * Cn);
                Cn2.y = Cn; Hn.y = O * tanhf_(Cn);
            }
            *(float2*)(Cst + idx) = Cn2;
            *(__half2*)(THall + idx) = __float22half2_rn(make_float2(Hn.x, Hn.y));
        }
    }
}

// out[perm[i]][p] = sum_h relu(H[i][h]) * W_lin[p][h] + b_lin[p]
__global__ void k_out(const __half* __restrict__ H, const float* __restrict__ W_lin,
                      const float* __restrict__ b_lin, const int* __restrict__ perm,
                      float* __restrict__ out, int N) {
    int idx = blockIdx.x * blockDim.x + threadIdx.x;
    if (idx >= N * PERIODS) return;
    int i = idx / PERIODS, p = idx % PERIODS;
    float acc = b_lin[p];
    const __half* Hp = H + (size_t)i * HID;
    #pragma unroll
    for (int h = 0; h < HID; ++h)
        acc += fmaxf(__half2float(Hp[h]), 0.f) * W_lin[p * HID + h];
    out[(size_t)perm[i] * PERIODS + p] = acc;
}

// ---------------- launch ----------------

extern "C" void kernel_launch(void* const* d_in, const int* in_sizes, int n_in,
                              void* d_out, int out_size, void* d_ws, size_t ws_size,
                              hipStream_t stream) {
    const float* xall  = (const float*)d_in[0];
    const int*   ei    = (const int*)d_in[1];
    const float* Wx    = (const float*)d_in[2];
    const float* Wh    = (const float*)d_in[3];
    const float* w_c   = (const float*)d_in[4];
    const float* bg    = (const float*)d_in[5];
    const float* W_lin = (const float*)d_in[6];
    const float* b_lin = (const float*)d_in[7];
    float* out = (float*)d_out;

    const int E = in_sizes[1] / 2;
    const int N = in_sizes[0] / (T_STEPS * F_IN);
    const int NT = (N + 255) / 256;
    const int* src = ei;
    const int* dst = ei + E;

    char* p = (char*)d_ws;
    auto carve = [&](size_t bytes) -> void* {
        void* r = (void*)p;
        p += (bytes + 255) & ~(size_t)255;
        return r;
    };
    // zero block: degi, cnt, fill, Cst, THall slice 0 (= H0)
    char* zero_begin = p;
    int*    degi  = (int*)   carve((size_t)N * 4);
    int*    cnt   = (int*)   carve((size_t)N * 4);
    int*    fill  = (int*)   carve((size_t)N * 4);
    float*  Cst   = (float*) carve((size_t)N * HID * 4);
    __half* THall = (__half*)carve((size_t)KCH * N * HID * 2);
    size_t zero_bytes = (size_t)((char*)THall - zero_begin) + (size_t)N * HID * 2;
    int*    hist     = (int*)   carve((size_t)256 * NT * 4);
    int*    histbase = (int*)   carve(((size_t)256 * NT + 1) * 4);
    float*  dis      = (float*) carve((size_t)N * 4);
    int*    perm     = (int*)   carve((size_t)N * 4);
    int*    iperm    = (int*)   carve((size_t)N * 4);
    int*    cntp     = (int*)   carve((size_t)N * 4);
    int*    rowptr   = (int*)   carve((size_t)(N + 1) * 4);
    int2*   cv       = (int2*)  carve((size_t)E * 8);
    __half* xb       = (__half*)carve((size_t)N * 64 * 2);
    __half* TXB      = (__half*)carve((size_t)4 * N * 64 * 2);

    hipMemsetAsync(zero_begin, 0, zero_bytes, stream);

    const int TB = 256;
    const int gE = (E + TB - 1) / TB;
    k_count<<<gE, TB, 0, stream>>>(src, dst, degi, cnt, E);
    k_hist2<<<NT, TB, 0, stream>>>(cnt, hist, N, NT);
    k_scan<<<1, 1024, 0, stream>>>(hist, histbase, 256 * NT);
    k_permscat2<<<NT, TB, 0, stream>>>(cnt, degi, histbase, perm, iperm, cntp, dis, N, NT);
    k_scan<<<1, 1024, 0, stream>>>(cntp, rowptr, N);
    k_scatter<<<gE, TB, 0, stream>>>(src, dst, dis, rowptr, iperm, fill, cv, E);
    k_xt<<<(N * T_STEPS + TB - 1) / TB, TB, 0, stream>>>(xall, iperm, xb, N);

    // batched x-phase Chebyshev terms over all timesteps (C = 64 halves)
    __half* TXB0 = TXB;
    __half* TXB1 = TXB + (size_t)N * 64;
    __half* TXB2 = TXB + (size_t)2 * N * 64;
    __half* TXB3 = TXB + (size_t)3 * N * 64;
    const int lapx_grid = (N * 16 + TB - 1) / TB;   // W = 16 lanes/node
    k_lap_h<64><<<lapx_grid, TB, 0, stream>>>(TXB0, xb,   nullptr, 1.f,  0.f, rowptr, cv, N);
    k_lap_h<64><<<lapx_grid, TB, 0, stream>>>(TXB1, TXB0, xb,      2.f, -1.f, rowptr, cv, N);
    k_lap_h<64><<<lapx_grid, TB, 0, stream>>>(TXB2, TXB1, TXB0,    2.f, -1.f, rowptr, cv, N);
    k_lap_h<64><<<lapx_grid, TB, 0, stream>>>(TXB3, TXB2, TXB1,    2.f, -1.f, rowptr, cv, N);

    const int laph_grid = (N * 8 + TB - 1) / TB;    // W = 8 lanes/node
    const int step_grid = (N + NB - 1) / NB;
    __half* TH0 = THall;
    __half* TH1 = THall + (size_t)N * HID;
    __half* TH2 = THall + (size_t)2 * N * HID;
    __half* TH3 = THall + (size_t)3 * N * HID;
    __half* TH4 = THall + (size_t)4 * N * HID;

    for (int t = 0; t < T_STEPS; ++t) {
        if (t > 0) {   // H-terms all zero at t=0 (H0 = 0): skip laps
            k_lap_h<HID><<<laph_grid, TB, 0, stream>>>(TH1, TH0, nullptr, 1.f,  0.f, rowptr, cv, N);
            k_lap_h<HID><<<laph_grid, TB, 0, stream>>>(TH2, TH1, TH0,     2.f, -1.f, rowptr, cv, N);
            k_lap_h<HID><<<laph_grid, TB, 0, stream>>>(TH3, TH2, TH1,     2.f, -1.f, rowptr, cv, N);
            k_lap_h<HID><<<laph_grid, TB, 0, stream>>>(TH4, TH3, TH2,     2.f, -1.f, rowptr, cv, N);
        }
        k_step<<<step_grid, TB, 0, stream>>>(xb, TXB, THall, Cst, Wx, Wh, w_c, bg,
                                             t, (t > 0) ? 1 : 0, N);
    }

    k_out<<<(N * PERIODS + TB - 1) / TB, TB, 0, stream>>>(TH0, W_lin, b_lin, perm, out, N);
}